// Round 8
// baseline (450.113 us; speedup 1.0000x reference)
//
#include <hip/hip_runtime.h>
#include <hip/hip_fp16.h>

constexpr int HEADS = 4;

typedef _Float16 half8 __attribute__((ext_vector_type(8)));
typedef _Float16 half2v __attribute__((ext_vector_type(2)));
typedef float f32x4 __attribute__((ext_vector_type(4)));

__device__ __forceinline__ float lrelu(float x) { return x > 0.f ? x : 0.2f * x; }

// ---------------- CSR build (edges grouped by dst; reused by all 3 layers) ----------------

__global__ void count_deg_kernel(const int* __restrict__ ei, int* __restrict__ deg,
                                 int E, int N) {
  int e = blockIdx.x * 256 + threadIdx.x;
  int EP = E + N;
  if (e < EP) {
    int d = (e < E) ? ei[E + e] : (e - E);   // self-loop tail
    atomicAdd(&deg[d], 1);
  }
}

__global__ void scan_block_kernel(const int* __restrict__ deg, int* __restrict__ rowp,
                                  int* __restrict__ partials, int N) {
  __shared__ int sm[1024];
  int t = threadIdx.x;
  int i = blockIdx.x * 1024 + t;
  int v = (i < N) ? deg[i] : 0;
  sm[t] = v;
  __syncthreads();
  for (int off = 1; off < 1024; off <<= 1) {
    int tmp = (t >= off) ? sm[t - off] : 0;
    __syncthreads();
    sm[t] += tmp;
    __syncthreads();
  }
  if (i < N) rowp[i] = sm[t] - v;            // exclusive within block
  if (t == 1023) partials[blockIdx.x] = sm[t];
}

// single 1024-thr block LDS scan (nb <= 1024)
__global__ void scan_partials_kernel(int* partials, int nb) {
  __shared__ int sm[1024];
  int t = threadIdx.x;
  int v = (t < nb) ? partials[t] : 0;
  sm[t] = v;
  __syncthreads();
  for (int off = 1; off < 1024; off <<= 1) {
    int tmp = (t >= off) ? sm[t - off] : 0;
    __syncthreads();
    sm[t] += tmp;
    __syncthreads();
  }
  if (t < nb) partials[t] = sm[t] - v;       // exclusive
}

__global__ void add_off_kernel(int* __restrict__ rowp, const int* __restrict__ partials,
                               int N, int EP) {
  int i = blockIdx.x * 256 + threadIdx.x;
  if (i < N) rowp[i] += partials[i >> 10];
  if (i == 0) rowp[N] = EP;
}

__global__ void scatter_kernel(const int* __restrict__ ei, const int* __restrict__ rowp,
                               int* __restrict__ cursor, int* __restrict__ col,
                               int* __restrict__ dstarr, int E, int N) {
  int e = blockIdx.x * 256 + threadIdx.x;
  int EP = E + N;
  if (e < EP) {
    int s, d;
    if (e < E) { s = ei[e]; d = ei[E + e]; }
    else       { s = e - E; d = e - E; }
    int pos = rowp[d] + atomicAdd(&cursor[d], 1);
    col[pos] = s;
    dstarr[pos] = d;
  }
}

// ---------------- weight transpose+convert: W [128,Fout] fp32 -> Wt [Fout,128] fp16 ----

__global__ void convert_wt3_kernel(const float* __restrict__ W1, _Float16* __restrict__ Wt1,
                                   const float* __restrict__ W2, _Float16* __restrict__ Wt2,
                                   const float* __restrict__ W3, _Float16* __restrict__ Wt3) {
  const float* W; _Float16* Wt; int Fout;
  if (blockIdx.y == 0)      { W = W1; Wt = Wt1; Fout = 128; }
  else if (blockIdx.y == 1) { W = W2; Wt = Wt2; Fout = 128; }
  else                      { W = W3; Wt = Wt3; Fout = 256; }
  int i = blockIdx.x * 256 + threadIdx.x;
  if (i < 128 * Fout) {
    int c = i >> 7, k = i & 127;
    Wt[c * 128 + k] = (_Float16)W[k * Fout + c];
  }
}

// ---------------- MFMA GEMM: A [N,128] (f32 or f16) @ Wt [Fout,128] f16 -> O f16 ----
// AF32=1: A is fp32, converted in-register (saves the separate convert pass).

template <int AF32>
__global__ __launch_bounds__(256) void gemm_mfma_kernel(
    const void* __restrict__ Xv, const _Float16* __restrict__ Wt,
    _Float16* __restrict__ O, int N, int Fout) {
  const int w = threadIdx.x >> 6;
  const int lane = threadIdx.x & 63;
  const int r = lane & 15, g = lane >> 4;
  const int row0 = blockIdx.x * 64 + w * 16;
  const int colpan = blockIdx.y * 128;

  int rowl = row0 + r;
  if (rowl >= N) rowl = N - 1;                     // clamp for loads; store guarded

  f32x4 acc[8];
#pragma unroll
  for (int c = 0; c < 8; ++c) acc[c] = {0.f, 0.f, 0.f, 0.f};

#pragma unroll
  for (int s = 0; s < 4; ++s) {
    half8 a;
    if constexpr (AF32) {
      const float* X = (const float*)Xv;
      float4 a0 = *(const float4*)&X[(size_t)rowl * 128 + s * 32 + g * 8];
      float4 a1 = *(const float4*)&X[(size_t)rowl * 128 + s * 32 + g * 8 + 4];
      a = half8{(_Float16)a0.x, (_Float16)a0.y, (_Float16)a0.z, (_Float16)a0.w,
                (_Float16)a1.x, (_Float16)a1.y, (_Float16)a1.z, (_Float16)a1.w};
    } else {
      const _Float16* X = (const _Float16*)Xv;
      a = *(const half8*)&X[(size_t)rowl * 128 + s * 32 + g * 8];
    }
#pragma unroll
    for (int c = 0; c < 8; ++c) {
      half8 b = *(const half8*)&Wt[(size_t)(colpan + c * 16 + r) * 128 + s * 32 + g * 8];
      acc[c] = __builtin_amdgcn_mfma_f32_16x16x32_f16(a, b, acc[c], 0, 0, 0);
    }
  }

#pragma unroll
  for (int c = 0; c < 8; ++c) {
    int ocol = colpan + c * 16 + r;
#pragma unroll
    for (int q = 0; q < 4; ++q) {
      int orow = row0 + g * 4 + q;
      if (orow < N) O[(size_t)orow * Fout + ocol] = (_Float16)acc[c][q];
    }
  }
}

// ---------------- per-node attention logits, vectorized ----------------

template <int LP>
__global__ __launch_bounds__(256) void alpha_kernel(
    const _Float16* __restrict__ H, const float* __restrict__ a_s,
    const float* __restrict__ a_d, float* __restrict__ asrc,
    float* __restrict__ adst, int N) {
  const int C = LP * 8;
  int g = blockIdx.x * 256 + threadIdx.x;
  int pair = g / LP;                 // n*4 + h
  int sub = g % LP;
  if (pair >= N * 4) return;
  int h = pair & 3;
  half8 hv = *(const half8*)&H[(size_t)pair * C + sub * 8];
  float4 s0 = *(const float4*)&a_s[h * C + sub * 8];
  float4 s1 = *(const float4*)&a_s[h * C + sub * 8 + 4];
  float4 d0 = *(const float4*)&a_d[h * C + sub * 8];
  float4 d1 = *(const float4*)&a_d[h * C + sub * 8 + 4];
  float ps = (float)hv[0] * s0.x + (float)hv[1] * s0.y + (float)hv[2] * s0.z +
             (float)hv[3] * s0.w + (float)hv[4] * s1.x + (float)hv[5] * s1.y +
             (float)hv[6] * s1.z + (float)hv[7] * s1.w;
  float pd = (float)hv[0] * d0.x + (float)hv[1] * d0.y + (float)hv[2] * d0.z +
             (float)hv[3] * d0.w + (float)hv[4] * d1.x + (float)hv[5] * d1.y +
             (float)hv[6] * d1.z + (float)hv[7] * d1.w;
#pragma unroll
  for (int off = 1; off < LP; off <<= 1) {
    ps += __shfl_xor(ps, off, 64);
    pd += __shfl_xor(pd, off, 64);
  }
  if (sub == 0) { asrc[pair] = ps; adst[pair] = pd; }
}

// ---------------- per-edge softmax weights (fp32, once per (edge,head)) ----------------

__global__ __launch_bounds__(256) void ew_kernel(
    const int* __restrict__ col, const int* __restrict__ dstarr,
    const float* __restrict__ asrc, const float* __restrict__ adst,
    float* __restrict__ wgt, int EP) {
  int j = blockIdx.x * 256 + threadIdx.x;
  if (j < EP) {
    int s = col[j], d = dstarr[j];
    float4 a = *(const float4*)&asrc[s * 4];
    float4 b = *(const float4*)&adst[d * 4];
    float4 o;
    o.x = __expf(lrelu(a.x + b.x));
    o.y = __expf(lrelu(a.y + b.y));
    o.z = __expf(lrelu(a.z + b.z));
    o.w = __expf(lrelu(a.w + b.w));
    *(float4*)&wgt[(size_t)j * 4] = o;
  }
}

// ---------------- atomic-free aggregation, unroll-8 (guarded main + scalar tail) ----
// 4 waves per block = 4 nodes; lane handles one half2 (2 of 128 ch).

__global__ __launch_bounds__(256) void aggregate_concat_kernel(
    const _Float16* __restrict__ H, const float* __restrict__ wgt,
    const float* __restrict__ bias, const int* __restrict__ rowp,
    const int* __restrict__ col, _Float16* __restrict__ out, int N) {
  int n = blockIdx.x * 4 + (threadIdx.x >> 6);
  if (n >= N) return;
  int lane = threadIdx.x & 63;     // channels 2*lane, 2*lane+1
  int h = lane >> 4;               // 16 lanes per head (32 ch)
  int j = rowp[n], end = rowp[n + 1];
  float ax = 0.f, ay = 0.f, denom = 0.f;
  for (; j + 7 < end; j += 8) {
    int s[8]; float w[8]; half2v f[8];
#pragma unroll
    for (int k = 0; k < 8; ++k) s[k] = col[j + k];
#pragma unroll
    for (int k = 0; k < 8; ++k) {
      w[k] = wgt[(size_t)(j + k) * 4 + h];
      f[k] = *(const half2v*)&H[(size_t)s[k] * 128 + lane * 2];
    }
#pragma unroll
    for (int k = 0; k < 8; ++k) {
      denom += w[k];
      ax += w[k] * (float)f[k].x;
      ay += w[k] * (float)f[k].y;
    }
  }
  for (; j < end; ++j) {
    int s0 = col[j];
    float w0 = wgt[(size_t)j * 4 + h];
    half2v f0 = *(const half2v*)&H[(size_t)s0 * 128 + lane * 2];
    denom += w0;
    ax += w0 * (float)f0.x;
    ay += w0 * (float)f0.y;
  }
  float inv = 1.f / denom;
  half2v o;
  o.x = (_Float16)(ax * inv + bias[lane * 2]);
  o.y = (_Float16)(ay * inv + bias[lane * 2 + 1]);
  *(half2v*)&out[(size_t)n * 128 + lane * 2] = o;
}

// layer 3: H rows 256 ch fp16; 128 thr/node; mean over 4 heads -> 64 ch fp32 out.

__global__ __launch_bounds__(128) void aggregate_mean_kernel(
    const _Float16* __restrict__ H, const float* __restrict__ wgt,
    const float* __restrict__ bias, const int* __restrict__ rowp,
    const int* __restrict__ col, float* __restrict__ out, int N) {
  __shared__ float2 red[128];
  int n = blockIdx.x;
  int t = threadIdx.x;             // channels 2t, 2t+1
  int h = t >> 5;                  // 32 threads per head (64 ch)
  int j = rowp[n], end = rowp[n + 1];
  float ax = 0.f, ay = 0.f, denom = 0.f;
  for (; j + 7 < end; j += 8) {
    int s[8]; float w[8]; half2v f[8];
#pragma unroll
    for (int k = 0; k < 8; ++k) s[k] = col[j + k];
#pragma unroll
    for (int k = 0; k < 8; ++k) {
      w[k] = wgt[(size_t)(j + k) * 4 + h];
      f[k] = *(const half2v*)&H[(size_t)s[k] * 256 + t * 2];
    }
#pragma unroll
    for (int k = 0; k < 8; ++k) {
      denom += w[k];
      ax += w[k] * (float)f[k].x;
      ay += w[k] * (float)f[k].y;
    }
  }
  for (; j < end; ++j) {
    int s0 = col[j];
    float w0 = wgt[(size_t)j * 4 + h];
    half2v f0 = *(const half2v*)&H[(size_t)s0 * 256 + t * 2];
    denom += w0;
    ax += w0 * (float)f0.x;
    ay += w0 * (float)f0.y;
  }
  float inv = 1.f / denom;
  red[t] = make_float2(ax * inv, ay * inv);
  __syncthreads();
  if (t < 32) {
    float2 r0 = red[t], r1 = red[t + 32], r2 = red[t + 64], r3 = red[t + 96];
    float2 o = make_float2(0.25f * (r0.x + r1.x + r2.x + r3.x) + bias[t * 2],
                           0.25f * (r0.y + r1.y + r2.y + r3.y) + bias[t * 2 + 1]);
    *(float2*)&out[n * 64 + t * 2] = o;
  }
}

// ---------------- host launch ----------------

extern "C" void kernel_launch(void* const* d_in, const int* in_sizes, int n_in,
                              void* d_out, int out_size, void* d_ws, size_t ws_size,
                              hipStream_t stream) {
  const float* x   = (const float*)d_in[0];
  const int*   ei  = (const int*)d_in[1];
  const float* W1  = (const float*)d_in[2];
  const float* as1 = (const float*)d_in[3];
  const float* ad1 = (const float*)d_in[4];
  const float* b1  = (const float*)d_in[5];
  const float* W2  = (const float*)d_in[6];
  const float* as2 = (const float*)d_in[7];
  const float* ad2 = (const float*)d_in[8];
  const float* b2  = (const float*)d_in[9];
  const float* W3  = (const float*)d_in[10];
  const float* as3 = (const float*)d_in[11];
  const float* ad3 = (const float*)d_in[12];
  const float* b3  = (const float*)d_in[13];
  float* out = (float*)d_out;

  const int N  = in_sizes[0] / 128;
  const int E  = in_sizes[1] / 2;
  const int EP = E + N;

  char* p = (char*)d_ws;
  auto carve = [&](size_t bytes) -> void* {
    void* r = (void*)p;
    p += (bytes + 255) & ~size_t(255);
    return r;
  };
  int*      deg  = (int*)carve(size_t(N) * 4);
  int*      rowp = (int*)carve(size_t(N + 1) * 4);
  int*      cur  = (int*)carve(size_t(N) * 4);
  int*      part = (int*)carve(1024 * 4);
  int*      col  = (int*)carve(size_t(EP) * 4);
  int*      darr = (int*)carve(size_t(EP) * 4);
  float*    asrc = (float*)carve(size_t(N) * HEADS * 4);
  float*    adst = (float*)carve(size_t(N) * HEADS * 4);
  float*    wgt  = (float*)carve(size_t(EP) * HEADS * 4);
  _Float16* Wt1  = (_Float16*)carve(128 * 128 * 2);
  _Float16* Wt2  = (_Float16*)carve(128 * 128 * 2);
  _Float16* Wt3  = (_Float16*)carve(256 * 128 * 2);
  _Float16* Hb   = (_Float16*)carve(size_t(N) * 256 * 2);  // gemm outputs
  _Float16* Ab   = (_Float16*)carve(size_t(N) * 128 * 2);  // aggregation outputs

  hipMemsetAsync(deg, 0, size_t(N) * 4, stream);
  hipMemsetAsync(cur, 0, size_t(N) * 4, stream);

  int gEP = (EP + 255) / 256;
  count_deg_kernel<<<gEP, 256, 0, stream>>>(ei, deg, E, N);
  int nb = (N + 1023) / 1024;
  scan_block_kernel<<<nb, 1024, 0, stream>>>(deg, rowp, part, N);
  scan_partials_kernel<<<1, 1024, 0, stream>>>(part, nb);
  add_off_kernel<<<(N + 256) / 256, 256, 0, stream>>>(rowp, part, N, EP);
  scatter_kernel<<<gEP, 256, 0, stream>>>(ei, rowp, cur, col, darr, E, N);

  convert_wt3_kernel<<<dim3(128, 3), 256, 0, stream>>>(W1, Wt1, W2, Wt2, W3, Wt3);

  int gM = (N + 63) / 64;
  int gN4 = (N + 3) / 4;
  int gA32 = (N * 4 * 4 + 255) / 256;   // alpha LP=4 (C=32)
  int gA64 = (N * 4 * 8 + 255) / 256;   // alpha LP=8 (C=64)

  // layer 1 (A = x fp32, converted in-register)
  gemm_mfma_kernel<1><<<dim3(gM, 1), 256, 0, stream>>>(x, Wt1, Hb, N, 128);
  alpha_kernel<4><<<gA32, 256, 0, stream>>>(Hb, as1, ad1, asrc, adst, N);
  ew_kernel<<<gEP, 256, 0, stream>>>(col, darr, asrc, adst, wgt, EP);
  aggregate_concat_kernel<<<gN4, 256, 0, stream>>>(Hb, wgt, b1, rowp, col, Ab, N);
  // layer 2
  gemm_mfma_kernel<0><<<dim3(gM, 1), 256, 0, stream>>>(Ab, Wt2, Hb, N, 128);
  alpha_kernel<4><<<gA32, 256, 0, stream>>>(Hb, as2, ad2, asrc, adst, N);
  ew_kernel<<<gEP, 256, 0, stream>>>(col, darr, asrc, adst, wgt, EP);
  aggregate_concat_kernel<<<gN4, 256, 0, stream>>>(Hb, wgt, b2, rowp, col, Ab, N);
  // layer 3 (Fout=256, mean over heads)
  gemm_mfma_kernel<0><<<dim3(gM, 2), 256, 0, stream>>>(Ab, Wt3, Hb, N, 256);
  alpha_kernel<8><<<gA64, 256, 0, stream>>>(Hb, as3, ad3, asrc, adst, N);
  ew_kernel<<<gEP, 256, 0, stream>>>(col, darr, asrc, adst, wgt, EP);
  aggregate_mean_kernel<<<N, 128, 0, stream>>>(Hb, wgt, b3, rowp, col, out, N);
}

// Round 9
// 422.523 us; speedup vs baseline: 1.0653x; 1.0653x over previous
//
#include <hip/hip_runtime.h>
#include <hip/hip_fp16.h>

constexpr int HEADS = 4;

typedef _Float16 half8 __attribute__((ext_vector_type(8)));
typedef _Float16 half2v __attribute__((ext_vector_type(2)));
typedef float f32x4 __attribute__((ext_vector_type(4)));

__device__ __forceinline__ float lrelu(float x) { return x > 0.f ? x : 0.2f * x; }

// ---------------- CSR build (edges grouped by dst; reused by all 3 layers) ----------------

__global__ void count_deg_kernel(const int* __restrict__ ei, int* __restrict__ deg,
                                 int E, int N) {
  int e = blockIdx.x * 256 + threadIdx.x;
  int EP = E + N;
  if (e < EP) {
    int d = (e < E) ? ei[E + e] : (e - E);   // self-loop tail
    atomicAdd(&deg[d], 1);
  }
}

__global__ void scan_block_kernel(const int* __restrict__ deg, int* __restrict__ rowp,
                                  int* __restrict__ partials, int N) {
  __shared__ int sm[1024];
  int t = threadIdx.x;
  int i = blockIdx.x * 1024 + t;
  int v = (i < N) ? deg[i] : 0;
  sm[t] = v;
  __syncthreads();
  for (int off = 1; off < 1024; off <<= 1) {
    int tmp = (t >= off) ? sm[t - off] : 0;
    __syncthreads();
    sm[t] += tmp;
    __syncthreads();
  }
  if (i < N) rowp[i] = sm[t] - v;            // exclusive within block
  if (t == 1023) partials[blockIdx.x] = sm[t];
}

// single 1024-thr block LDS scan (nb <= 1024)
__global__ void scan_partials_kernel(int* partials, int nb) {
  __shared__ int sm[1024];
  int t = threadIdx.x;
  int v = (t < nb) ? partials[t] : 0;
  sm[t] = v;
  __syncthreads();
  for (int off = 1; off < 1024; off <<= 1) {
    int tmp = (t >= off) ? sm[t - off] : 0;
    __syncthreads();
    sm[t] += tmp;
    __syncthreads();
  }
  if (t < nb) partials[t] = sm[t] - v;       // exclusive
}

__global__ void add_off_kernel(int* __restrict__ rowp, const int* __restrict__ partials,
                               int N, int EP) {
  int i = blockIdx.x * 256 + threadIdx.x;
  if (i < N) rowp[i] += partials[i >> 10];
  if (i == 0) rowp[N] = EP;
}

__global__ void scatter_kernel(const int* __restrict__ ei, const int* __restrict__ rowp,
                               int* __restrict__ cursor, int* __restrict__ col,
                               int E, int N) {
  int e = blockIdx.x * 256 + threadIdx.x;
  int EP = E + N;
  if (e < EP) {
    int s, d;
    if (e < E) { s = ei[e]; d = ei[E + e]; }
    else       { s = e - E; d = e - E; }
    int pos = rowp[d] + atomicAdd(&cursor[d], 1);
    col[pos] = s;
  }
}

// ---------------- weight transpose+convert: W [128,Fout] fp32 -> Wt [Fout,128] fp16 ----

__global__ void convert_wt3_kernel(const float* __restrict__ W1, _Float16* __restrict__ Wt1,
                                   const float* __restrict__ W2, _Float16* __restrict__ Wt2,
                                   const float* __restrict__ W3, _Float16* __restrict__ Wt3) {
  const float* W; _Float16* Wt; int Fout;
  if (blockIdx.y == 0)      { W = W1; Wt = Wt1; Fout = 128; }
  else if (blockIdx.y == 1) { W = W2; Wt = Wt2; Fout = 128; }
  else                      { W = W3; Wt = Wt3; Fout = 256; }
  int i = blockIdx.x * 256 + threadIdx.x;
  if (i < 128 * Fout) {
    int c = i >> 7, k = i & 127;
    Wt[c * 128 + k] = (_Float16)W[k * Fout + c];
  }
}

// ---------------- MFMA GEMM + fused alpha epilogue ----------------
// A [N,128] (f32 or f16) @ Wt [Fout,128] f16 -> O [N,Fout] f16, plus
// asrc[n,h] = sum_c h[n,h,c]*a_s[h,c], adst likewise, computed from fp32 acc.
// C/D frag: col = c*16 + (lane&15), rows = (lane>>4)*4 + q.
// CPH = MFMA col-tiles per head (2 -> C=32, 4 -> C=64). heads/panel = 8/CPH.

template <int AF32, int CPH>
__global__ __launch_bounds__(256) void gemm_mfma_kernel(
    const void* __restrict__ Xv, const _Float16* __restrict__ Wt,
    const float* __restrict__ a_s, const float* __restrict__ a_d,
    _Float16* __restrict__ O, float* __restrict__ asrc, float* __restrict__ adst,
    int N, int Fout) {
  const int w = threadIdx.x >> 6;
  const int lane = threadIdx.x & 63;
  const int r = lane & 15, g = lane >> 4;
  const int row0 = blockIdx.x * 64 + w * 16;
  const int colpan = blockIdx.y * 128;

  int rowl = row0 + r;
  if (rowl >= N) rowl = N - 1;                     // clamp for loads; stores guarded

  f32x4 acc[8];
#pragma unroll
  for (int c = 0; c < 8; ++c) acc[c] = {0.f, 0.f, 0.f, 0.f};

#pragma unroll
  for (int s = 0; s < 4; ++s) {
    half8 a;
    if constexpr (AF32) {
      const float* X = (const float*)Xv;
      float4 a0 = *(const float4*)&X[(size_t)rowl * 128 + s * 32 + g * 8];
      float4 a1 = *(const float4*)&X[(size_t)rowl * 128 + s * 32 + g * 8 + 4];
      a = half8{(_Float16)a0.x, (_Float16)a0.y, (_Float16)a0.z, (_Float16)a0.w,
                (_Float16)a1.x, (_Float16)a1.y, (_Float16)a1.z, (_Float16)a1.w};
    } else {
      const _Float16* X = (const _Float16*)Xv;
      a = *(const half8*)&X[(size_t)rowl * 128 + s * 32 + g * 8];
    }
#pragma unroll
    for (int c = 0; c < 8; ++c) {
      half8 b = *(const half8*)&Wt[(size_t)(colpan + c * 16 + r) * 128 + s * 32 + g * 8];
      acc[c] = __builtin_amdgcn_mfma_f32_16x16x32_f16(a, b, acc[c], 0, 0, 0);
    }
  }

  // store O
#pragma unroll
  for (int c = 0; c < 8; ++c) {
    int ocol = colpan + c * 16 + r;
#pragma unroll
    for (int q = 0; q < 4; ++q) {
      int orow = row0 + g * 4 + q;
      if (orow < N) O[(size_t)orow * Fout + ocol] = (_Float16)acc[c][q];
    }
  }

  // fused alpha: per-lane partials over this lane's column, then reduce over r-lanes
  constexpr int HPP = 8 / CPH;          // heads in this panel
  constexpr int C = CPH * 16;           // channels per head
  const int hbase = blockIdx.y * HPP;
  float ps[4][HPP], pd[4][HPP];
#pragma unroll
  for (int q = 0; q < 4; ++q)
#pragma unroll
    for (int hh = 0; hh < HPP; ++hh) { ps[q][hh] = 0.f; pd[q][hh] = 0.f; }

#pragma unroll
  for (int c = 0; c < 8; ++c) {
    int hh = c / CPH;
    int ch = (c % CPH) * 16 + r;
    float asv = a_s[(hbase + hh) * C + ch];
    float adv = a_d[(hbase + hh) * C + ch];
#pragma unroll
    for (int q = 0; q < 4; ++q) {
      ps[q][hh] += acc[c][q] * asv;
      pd[q][hh] += acc[c][q] * adv;
    }
  }
#pragma unroll
  for (int m = 1; m < 16; m <<= 1) {
#pragma unroll
    for (int q = 0; q < 4; ++q)
#pragma unroll
      for (int hh = 0; hh < HPP; ++hh) {
        ps[q][hh] += __shfl_xor(ps[q][hh], m, 64);
        pd[q][hh] += __shfl_xor(pd[q][hh], m, 64);
      }
  }
  if (r == 0) {
#pragma unroll
    for (int q = 0; q < 4; ++q) {
      int row = row0 + g * 4 + q;
      if (row < N) {
#pragma unroll
        for (int hh = 0; hh < HPP; ++hh) {
          asrc[row * 4 + hbase + hh] = ps[q][hh];
          adst[row * 4 + hbase + hh] = pd[q][hh];
        }
      }
    }
  }
}

// ---------------- aggregation, inline softmax weights, unroll-8 ----------------
// 4 waves per block = 4 nodes; lane handles one half2 (2 of 128 ch).
// w = exp(lrelu(asrc[s,h] + adst[n,h])) computed inline (asrc table is L2-resident).

__global__ __launch_bounds__(256) void aggregate_concat_kernel(
    const _Float16* __restrict__ H, const float* __restrict__ asrc,
    const float* __restrict__ adst, const float* __restrict__ bias,
    const int* __restrict__ rowp, const int* __restrict__ col,
    _Float16* __restrict__ out, int N) {
  int n = blockIdx.x * 4 + (threadIdx.x >> 6);
  if (n >= N) return;
  int lane = threadIdx.x & 63;     // channels 2*lane, 2*lane+1
  int h = lane >> 4;               // 16 lanes per head (32 ch)
  float ad = adst[n * 4 + h];
  int j = rowp[n], end = rowp[n + 1];
  float ax = 0.f, ay = 0.f, denom = 0.f;
  for (; j + 7 < end; j += 8) {
    int s[8]; float w[8]; half2v f[8];
#pragma unroll
    for (int k = 0; k < 8; ++k) s[k] = col[j + k];
#pragma unroll
    for (int k = 0; k < 8; ++k) {
      w[k] = __expf(lrelu(asrc[s[k] * 4 + h] + ad));
      f[k] = *(const half2v*)&H[(size_t)s[k] * 128 + lane * 2];
    }
#pragma unroll
    for (int k = 0; k < 8; ++k) {
      denom += w[k];
      ax += w[k] * (float)f[k].x;
      ay += w[k] * (float)f[k].y;
    }
  }
  for (; j < end; ++j) {
    int s0 = col[j];
    float w0 = __expf(lrelu(asrc[s0 * 4 + h] + ad));
    half2v f0 = *(const half2v*)&H[(size_t)s0 * 128 + lane * 2];
    denom += w0;
    ax += w0 * (float)f0.x;
    ay += w0 * (float)f0.y;
  }
  float inv = 1.f / denom;
  half2v o;
  o.x = (_Float16)(ax * inv + bias[lane * 2]);
  o.y = (_Float16)(ay * inv + bias[lane * 2 + 1]);
  *(half2v*)&out[(size_t)n * 128 + lane * 2] = o;
}

// layer 3: H rows 256 ch fp16; 128 thr/node; mean over 4 heads -> 64 ch fp32 out.

__global__ __launch_bounds__(128) void aggregate_mean_kernel(
    const _Float16* __restrict__ H, const float* __restrict__ asrc,
    const float* __restrict__ adst, const float* __restrict__ bias,
    const int* __restrict__ rowp, const int* __restrict__ col,
    float* __restrict__ out, int N) {
  __shared__ float2 red[128];
  int n = blockIdx.x;
  int t = threadIdx.x;             // channels 2t, 2t+1
  int h = t >> 5;                  // 32 threads per head (64 ch)
  float ad = adst[n * 4 + h];
  int j = rowp[n], end = rowp[n + 1];
  float ax = 0.f, ay = 0.f, denom = 0.f;
  for (; j + 7 < end; j += 8) {
    int s[8]; float w[8]; half2v f[8];
#pragma unroll
    for (int k = 0; k < 8; ++k) s[k] = col[j + k];
#pragma unroll
    for (int k = 0; k < 8; ++k) {
      w[k] = __expf(lrelu(asrc[s[k] * 4 + h] + ad));
      f[k] = *(const half2v*)&H[(size_t)s[k] * 256 + t * 2];
    }
#pragma unroll
    for (int k = 0; k < 8; ++k) {
      denom += w[k];
      ax += w[k] * (float)f[k].x;
      ay += w[k] * (float)f[k].y;
    }
  }
  for (; j < end; ++j) {
    int s0 = col[j];
    float w0 = __expf(lrelu(asrc[s0 * 4 + h] + ad));
    half2v f0 = *(const half2v*)&H[(size_t)s0 * 256 + t * 2];
    denom += w0;
    ax += w0 * (float)f0.x;
    ay += w0 * (float)f0.y;
  }
  float inv = 1.f / denom;
  red[t] = make_float2(ax * inv, ay * inv);
  __syncthreads();
  if (t < 32) {
    float2 r0 = red[t], r1 = red[t + 32], r2 = red[t + 64], r3 = red[t + 96];
    float2 o = make_float2(0.25f * (r0.x + r1.x + r2.x + r3.x) + bias[t * 2],
                           0.25f * (r0.y + r1.y + r2.y + r3.y) + bias[t * 2 + 1]);
    *(float2*)&out[n * 64 + t * 2] = o;
  }
}

// ---------------- host launch ----------------

extern "C" void kernel_launch(void* const* d_in, const int* in_sizes, int n_in,
                              void* d_out, int out_size, void* d_ws, size_t ws_size,
                              hipStream_t stream) {
  const float* x   = (const float*)d_in[0];
  const int*   ei  = (const int*)d_in[1];
  const float* W1  = (const float*)d_in[2];
  const float* as1 = (const float*)d_in[3];
  const float* ad1 = (const float*)d_in[4];
  const float* b1  = (const float*)d_in[5];
  const float* W2  = (const float*)d_in[6];
  const float* as2 = (const float*)d_in[7];
  const float* ad2 = (const float*)d_in[8];
  const float* b2  = (const float*)d_in[9];
  const float* W3  = (const float*)d_in[10];
  const float* as3 = (const float*)d_in[11];
  const float* ad3 = (const float*)d_in[12];
  const float* b3  = (const float*)d_in[13];
  float* out = (float*)d_out;

  const int N  = in_sizes[0] / 128;
  const int E  = in_sizes[1] / 2;
  const int EP = E + N;

  char* p = (char*)d_ws;
  auto carve = [&](size_t bytes) -> void* {
    void* r = (void*)p;
    p += (bytes + 255) & ~size_t(255);
    return r;
  };
  int*      deg  = (int*)carve(size_t(N) * 4);
  int*      rowp = (int*)carve(size_t(N + 1) * 4);
  int*      cur  = (int*)carve(size_t(N) * 4);
  int*      part = (int*)carve(1024 * 4);
  int*      col  = (int*)carve(size_t(EP) * 4);
  float*    asrc = (float*)carve(size_t(N) * HEADS * 4);
  float*    adst = (float*)carve(size_t(N) * HEADS * 4);
  _Float16* Wt1  = (_Float16*)carve(128 * 128 * 2);
  _Float16* Wt2  = (_Float16*)carve(128 * 128 * 2);
  _Float16* Wt3  = (_Float16*)carve(256 * 128 * 2);
  _Float16* Hb   = (_Float16*)carve(size_t(N) * 256 * 2);  // gemm outputs
  _Float16* Ab   = (_Float16*)carve(size_t(N) * 128 * 2);  // aggregation outputs

  hipMemsetAsync(deg, 0, size_t(N) * 4, stream);
  hipMemsetAsync(cur, 0, size_t(N) * 4, stream);

  int gEP = (EP + 255) / 256;
  count_deg_kernel<<<gEP, 256, 0, stream>>>(ei, deg, E, N);
  int nb = (N + 1023) / 1024;
  scan_block_kernel<<<nb, 1024, 0, stream>>>(deg, rowp, part, N);
  scan_partials_kernel<<<1, 1024, 0, stream>>>(part, nb);
  add_off_kernel<<<(N + 256) / 256, 256, 0, stream>>>(rowp, part, N, EP);
  scatter_kernel<<<gEP, 256, 0, stream>>>(ei, rowp, cur, col, E, N);

  convert_wt3_kernel<<<dim3(128, 3), 256, 0, stream>>>(W1, Wt1, W2, Wt2, W3, Wt3);

  int gM = (N + 63) / 64;
  int gN4 = (N + 3) / 4;

  // layer 1 (A = x fp32 converted in-register; alpha fused into epilogue)
  gemm_mfma_kernel<1, 2><<<dim3(gM, 1), 256, 0, stream>>>(
      x, Wt1, as1, ad1, Hb, asrc, adst, N, 128);
  aggregate_concat_kernel<<<gN4, 256, 0, stream>>>(Hb, asrc, adst, b1, rowp, col, Ab, N);
  // layer 2
  gemm_mfma_kernel<0, 2><<<dim3(gM, 1), 256, 0, stream>>>(
      Ab, Wt2, as2, ad2, Hb, asrc, adst, N, 128);
  aggregate_concat_kernel<<<gN4, 256, 0, stream>>>(Hb, asrc, adst, b2, rowp, col, Ab, N);
  // layer 3 (Fout=256, C=64, two col-panels of 2 heads each; mean over heads)
  gemm_mfma_kernel<0, 4><<<dim3(gM, 2), 256, 0, stream>>>(
      Ab, Wt3, as3, ad3, Hb, asrc, adst, N, 256);
  aggregate_mean_kernel<<<N, 128, 0, stream>>>(Hb, asrc, adst, b3, rowp, col, out, N);
}

// Round 10
// 406.225 us; speedup vs baseline: 1.1080x; 1.0401x over previous
//
#include <hip/hip_runtime.h>
#include <hip/hip_fp16.h>

constexpr int HEADS = 4;

typedef _Float16 half8 __attribute__((ext_vector_type(8)));
typedef _Float16 half2v __attribute__((ext_vector_type(2)));
typedef float f32x4 __attribute__((ext_vector_type(4)));

__device__ __forceinline__ float lrelu(float x) { return x > 0.f ? x : 0.2f * x; }

// ---------------- CSR build (edges grouped by dst; reused by all 3 layers) ----------------

__global__ void count_deg_kernel(const int* __restrict__ ei, int* __restrict__ deg,
                                 int E, int N) {
  int e = blockIdx.x * 256 + threadIdx.x;
  int EP = E + N;
  if (e < EP) {
    int d = (e < E) ? ei[E + e] : (e - E);   // self-loop tail
    atomicAdd(&deg[d], 1);
  }
}

__global__ void scan_block_kernel(const int* __restrict__ deg, int* __restrict__ rowp,
                                  int* __restrict__ partials, int N) {
  __shared__ int sm[1024];
  int t = threadIdx.x;
  int i = blockIdx.x * 1024 + t;
  int v = (i < N) ? deg[i] : 0;
  sm[t] = v;
  __syncthreads();
  for (int off = 1; off < 1024; off <<= 1) {
    int tmp = (t >= off) ? sm[t - off] : 0;
    __syncthreads();
    sm[t] += tmp;
    __syncthreads();
  }
  if (i < N) rowp[i] = sm[t] - v;            // exclusive within block
  if (t == 1023) partials[blockIdx.x] = sm[t];
}

// single 1024-thr block LDS scan (nb <= 1024)
__global__ void scan_partials_kernel(int* partials, int nb) {
  __shared__ int sm[1024];
  int t = threadIdx.x;
  int v = (t < nb) ? partials[t] : 0;
  sm[t] = v;
  __syncthreads();
  for (int off = 1; off < 1024; off <<= 1) {
    int tmp = (t >= off) ? sm[t - off] : 0;
    __syncthreads();
    sm[t] += tmp;
    __syncthreads();
  }
  if (t < nb) partials[t] = sm[t] - v;       // exclusive
}

__global__ void add_off_kernel(int* __restrict__ rowp, const int* __restrict__ partials,
                               int N, int EP) {
  int i = blockIdx.x * 256 + threadIdx.x;
  if (i < N) rowp[i] += partials[i >> 10];
  if (i == 0) rowp[N] = EP;
}

__global__ void scatter_kernel(const int* __restrict__ ei, const int* __restrict__ rowp,
                               int* __restrict__ cursor, int* __restrict__ col,
                               int E, int N) {
  int e = blockIdx.x * 256 + threadIdx.x;
  int EP = E + N;
  if (e < EP) {
    int s, d;
    if (e < E) { s = ei[e]; d = ei[E + e]; }
    else       { s = e - E; d = e - E; }
    int pos = rowp[d] + atomicAdd(&cursor[d], 1);
    col[pos] = s;
  }
}

// ---------------- weight transpose+convert: W [128,Fout] fp32 -> Wt [Fout,128] fp16 ----

__global__ void convert_wt3_kernel(const float* __restrict__ W1, _Float16* __restrict__ Wt1,
                                   const float* __restrict__ W2, _Float16* __restrict__ Wt2,
                                   const float* __restrict__ W3, _Float16* __restrict__ Wt3) {
  const float* W; _Float16* Wt; int Fout;
  if (blockIdx.y == 0)      { W = W1; Wt = Wt1; Fout = 128; }
  else if (blockIdx.y == 1) { W = W2; Wt = Wt2; Fout = 128; }
  else                      { W = W3; Wt = Wt3; Fout = 256; }
  int i = blockIdx.x * 256 + threadIdx.x;
  if (i < 128 * Fout) {
    int c = i >> 7, k = i & 127;
    Wt[c * 128 + k] = (_Float16)W[k * Fout + c];
  }
}

// ---------------- MFMA GEMM v2: B panel staged in LDS (XOR-swizzled) + fused alpha ----
// A [N,128] (f32 or f16) @ Wt [Fout,128] f16 -> O [N,Fout] f16, plus
// asrc[n,h] = sum_c h[n,h,c]*a_s[h,c] (and adst) from the fp32 accumulators.
// B-frag per lane: 16B at row (c*16+r), bytes k: s*64 + g*16 (g = lane>>4 in 0..3).
// LDS swizzle: byte ^= (col&7)<<4 -> the 16-row-strided ds_read_b128 is <=2-way.

template <int AF32, int CPH>
__global__ __launch_bounds__(256) void gemm_mfma_kernel(
    const void* __restrict__ Xv, const _Float16* __restrict__ Wt,
    const float* __restrict__ a_s, const float* __restrict__ a_d,
    _Float16* __restrict__ O, float* __restrict__ asrc, float* __restrict__ adst,
    int N, int Fout) {
  __shared__ __align__(16) char Bl[32768];      // 128 cols x 128 k x 2B
  const int t = threadIdx.x;
  const int w = t >> 6;
  const int lane = t & 63;
  const int r = lane & 15, g = lane >> 4;
  const int row0 = blockIdx.x * 64 + w * 16;
  const int colpan = blockIdx.y * 128;

  // stage B panel: 2048 chunks of 16B; coalesced global read, swizzled LDS write
#pragma unroll
  for (int i = 0; i < 8; ++i) {
    int lin = i * 256 + t;                      // 16B chunk id
    int c0 = lin >> 4;                          // col 0..127
    int kb = lin & 15;                          // 16B chunk along k
    half8 v = *(const half8*)&Wt[(size_t)(colpan + c0) * 128 + kb * 8];
    int addr = (c0 * 256 + kb * 16) ^ ((c0 & 7) << 4);
    *(half8*)(Bl + addr) = v;
  }
  __syncthreads();

  int rowl = row0 + r;
  if (rowl >= N) rowl = N - 1;                  // clamp for loads; stores guarded

  f32x4 acc[8];
#pragma unroll
  for (int c = 0; c < 8; ++c) acc[c] = {0.f, 0.f, 0.f, 0.f};

#pragma unroll
  for (int s = 0; s < 4; ++s) {
    half8 a;
    if constexpr (AF32) {
      const float* X = (const float*)Xv;
      float4 a0 = *(const float4*)&X[(size_t)rowl * 128 + s * 32 + g * 8];
      float4 a1 = *(const float4*)&X[(size_t)rowl * 128 + s * 32 + g * 8 + 4];
      a = half8{(_Float16)a0.x, (_Float16)a0.y, (_Float16)a0.z, (_Float16)a0.w,
                (_Float16)a1.x, (_Float16)a1.y, (_Float16)a1.z, (_Float16)a1.w};
    } else {
      const _Float16* X = (const _Float16*)Xv;
      a = *(const half8*)&X[(size_t)rowl * 128 + s * 32 + g * 8];
    }
#pragma unroll
    for (int c = 0; c < 8; ++c) {
      int colr = c * 16 + r;
      int addr = (colr * 256 + s * 64 + g * 16) ^ ((colr & 7) << 4);
      half8 b = *(const half8*)(Bl + addr);
      acc[c] = __builtin_amdgcn_mfma_f32_16x16x32_f16(a, b, acc[c], 0, 0, 0);
    }
  }

  // store O
#pragma unroll
  for (int c = 0; c < 8; ++c) {
    int ocol = colpan + c * 16 + r;
#pragma unroll
    for (int q = 0; q < 4; ++q) {
      int orow = row0 + g * 4 + q;
      if (orow < N) O[(size_t)orow * Fout + ocol] = (_Float16)acc[c][q];
    }
  }

  // fused alpha epilogue: per-lane partials, reduce over the 16 r-lanes
  constexpr int HPP = 8 / CPH;          // heads in this panel
  constexpr int C = CPH * 16;           // channels per head
  const int hbase = blockIdx.y * HPP;
  float ps[4][HPP], pd[4][HPP];
#pragma unroll
  for (int q = 0; q < 4; ++q)
#pragma unroll
    for (int hh = 0; hh < HPP; ++hh) { ps[q][hh] = 0.f; pd[q][hh] = 0.f; }

#pragma unroll
  for (int c = 0; c < 8; ++c) {
    int hh = c / CPH;
    int ch = (c % CPH) * 16 + r;
    float asv = a_s[(hbase + hh) * C + ch];
    float adv = a_d[(hbase + hh) * C + ch];
#pragma unroll
    for (int q = 0; q < 4; ++q) {
      ps[q][hh] += acc[c][q] * asv;
      pd[q][hh] += acc[c][q] * adv;
    }
  }
#pragma unroll
  for (int m = 1; m < 16; m <<= 1) {
#pragma unroll
    for (int q = 0; q < 4; ++q)
#pragma unroll
      for (int hh = 0; hh < HPP; ++hh) {
        ps[q][hh] += __shfl_xor(ps[q][hh], m, 64);
        pd[q][hh] += __shfl_xor(pd[q][hh], m, 64);
      }
  }
  if (r == 0) {
#pragma unroll
    for (int q = 0; q < 4; ++q) {
      int row = row0 + g * 4 + q;
      if (row < N) {
#pragma unroll
        for (int hh = 0; hh < HPP; ++hh) {
          asrc[row * 4 + hbase + hh] = ps[q][hh];
          adst[row * 4 + hbase + hh] = pd[q][hh];
        }
      }
    }
  }
}

// ---------------- aggregation, exp-dedup via shuffle broadcast, unroll-8 ----------------
// concat: 4 waves per block = 4 nodes; lane handles one half2 (2 of 128 ch); h = lane>>4.
// Weight for (edge k, head h) computed ONCE by lane (h<<4)|k, broadcast via shfl.

__global__ __launch_bounds__(256) void aggregate_concat_kernel(
    const _Float16* __restrict__ H, const float* __restrict__ asrc,
    const float* __restrict__ adst, const float* __restrict__ bias,
    const int* __restrict__ rowp, const int* __restrict__ col,
    _Float16* __restrict__ out, int N) {
  int n = blockIdx.x * 4 + (threadIdx.x >> 6);
  if (n >= N) return;
  int lane = threadIdx.x & 63;     // channels 2*lane, 2*lane+1
  int h = lane >> 4;               // 16 lanes per head (32 ch)
  float ad = adst[n * 4 + h];
  int j = rowp[n], end = rowp[n + 1];
  const bool comp = (lane & 15) < 8;   // lanes (h<<4)|0..7 compute weights
  const int bsrc = lane & 48;          // shfl source base for own head
  float ax = 0.f, ay = 0.f, denom = 0.f;
  for (; j + 7 < end; j += 8) {
    float wpre = 0.f;
    if (comp) {
      int sc = col[j + (lane & 7)];
      wpre = __expf(lrelu(asrc[sc * 4 + h] + ad));
    }
    int s[8]; half2v f[8]; float wk[8];
#pragma unroll
    for (int k = 0; k < 8; ++k) s[k] = col[j + k];
#pragma unroll
    for (int k = 0; k < 8; ++k) {
      wk[k] = __shfl(wpre, bsrc | k, 64);
      f[k] = *(const half2v*)&H[(size_t)s[k] * 128 + lane * 2];
    }
#pragma unroll
    for (int k = 0; k < 8; ++k) {
      denom += wk[k];
      ax += wk[k] * (float)f[k].x;
      ay += wk[k] * (float)f[k].y;
    }
  }
  for (; j < end; ++j) {
    int s0 = col[j];
    float w0 = __expf(lrelu(asrc[s0 * 4 + h] + ad));
    half2v f0 = *(const half2v*)&H[(size_t)s0 * 128 + lane * 2];
    denom += w0;
    ax += w0 * (float)f0.x;
    ay += w0 * (float)f0.y;
  }
  float inv = 1.f / denom;
  half2v o;
  o.x = (_Float16)(ax * inv + bias[lane * 2]);
  o.y = (_Float16)(ay * inv + bias[lane * 2 + 1]);
  *(half2v*)&out[(size_t)n * 128 + lane * 2] = o;
}

// layer 3: H rows 256 ch fp16; 128 thr/node; h = t>>5 (2 heads per wave);
// weight for (edge k, head) computed by lanes (l&32)|0..7, broadcast via shfl.

__global__ __launch_bounds__(128) void aggregate_mean_kernel(
    const _Float16* __restrict__ H, const float* __restrict__ asrc,
    const float* __restrict__ adst, const float* __restrict__ bias,
    const int* __restrict__ rowp, const int* __restrict__ col,
    float* __restrict__ out, int N) {
  __shared__ float2 red[128];
  int n = blockIdx.x;
  int t = threadIdx.x;             // channels 2t, 2t+1
  int h = t >> 5;                  // 32 threads per head (64 ch)
  int lane = t & 63;
  float ad = adst[n * 4 + h];
  int j = rowp[n], end = rowp[n + 1];
  const bool comp = (lane & 31) < 8;   // lanes (hlocal<<5)|0..7 compute weights
  const int bsrc = lane & 32;
  float ax = 0.f, ay = 0.f, denom = 0.f;
  for (; j + 7 < end; j += 8) {
    float wpre = 0.f;
    if (comp) {
      int sc = col[j + (lane & 7)];
      wpre = __expf(lrelu(asrc[sc * 4 + h] + ad));
    }
    int s[8]; half2v f[8]; float wk[8];
#pragma unroll
    for (int k = 0; k < 8; ++k) s[k] = col[j + k];
#pragma unroll
    for (int k = 0; k < 8; ++k) {
      wk[k] = __shfl(wpre, bsrc | k, 64);
      f[k] = *(const half2v*)&H[(size_t)s[k] * 256 + t * 2];
    }
#pragma unroll
    for (int k = 0; k < 8; ++k) {
      denom += wk[k];
      ax += wk[k] * (float)f[k].x;
      ay += wk[k] * (float)f[k].y;
    }
  }
  for (; j < end; ++j) {
    int s0 = col[j];
    float w0 = __expf(lrelu(asrc[s0 * 4 + h] + ad));
    half2v f0 = *(const half2v*)&H[(size_t)s0 * 256 + t * 2];
    denom += w0;
    ax += w0 * (float)f0.x;
    ay += w0 * (float)f0.y;
  }
  float inv = 1.f / denom;
  red[t] = make_float2(ax * inv, ay * inv);
  __syncthreads();
  if (t < 32) {
    float2 r0 = red[t], r1 = red[t + 32], r2 = red[t + 64], r3 = red[t + 96];
    float2 o = make_float2(0.25f * (r0.x + r1.x + r2.x + r3.x) + bias[t * 2],
                           0.25f * (r0.y + r1.y + r2.y + r3.y) + bias[t * 2 + 1]);
    *(float2*)&out[n * 64 + t * 2] = o;
  }
}

// ---------------- host launch ----------------

extern "C" void kernel_launch(void* const* d_in, const int* in_sizes, int n_in,
                              void* d_out, int out_size, void* d_ws, size_t ws_size,
                              hipStream_t stream) {
  const float* x   = (const float*)d_in[0];
  const int*   ei  = (const int*)d_in[1];
  const float* W1  = (const float*)d_in[2];
  const float* as1 = (const float*)d_in[3];
  const float* ad1 = (const float*)d_in[4];
  const float* b1  = (const float*)d_in[5];
  const float* W2  = (const float*)d_in[6];
  const float* as2 = (const float*)d_in[7];
  const float* ad2 = (const float*)d_in[8];
  const float* b2  = (const float*)d_in[9];
  const float* W3  = (const float*)d_in[10];
  const float* as3 = (const float*)d_in[11];
  const float* ad3 = (const float*)d_in[12];
  const float* b3  = (const float*)d_in[13];
  float* out = (float*)d_out;

  const int N  = in_sizes[0] / 128;
  const int E  = in_sizes[1] / 2;
  const int EP = E + N;

  char* p = (char*)d_ws;
  auto carve = [&](size_t bytes) -> void* {
    void* r = (void*)p;
    p += (bytes + 255) & ~size_t(255);
    return r;
  };
  int*      deg  = (int*)carve(size_t(N) * 4);
  int*      rowp = (int*)carve(size_t(N + 1) * 4);
  int*      cur  = (int*)carve(size_t(N) * 4);
  int*      part = (int*)carve(1024 * 4);
  int*      col  = (int*)carve(size_t(EP) * 4);
  float*    asrc = (float*)carve(size_t(N) * HEADS * 4);
  float*    adst = (float*)carve(size_t(N) * HEADS * 4);
  _Float16* Wt1  = (_Float16*)carve(128 * 128 * 2);
  _Float16* Wt2  = (_Float16*)carve(128 * 128 * 2);
  _Float16* Wt3  = (_Float16*)carve(256 * 128 * 2);
  _Float16* Hb   = (_Float16*)carve(size_t(N) * 256 * 2);  // gemm outputs
  _Float16* Ab   = (_Float16*)carve(size_t(N) * 128 * 2);  // aggregation outputs

  hipMemsetAsync(deg, 0, size_t(N) * 4, stream);
  hipMemsetAsync(cur, 0, size_t(N) * 4, stream);

  int gEP = (EP + 255) / 256;
  count_deg_kernel<<<gEP, 256, 0, stream>>>(ei, deg, E, N);
  int nb = (N + 1023) / 1024;
  scan_block_kernel<<<nb, 1024, 0, stream>>>(deg, rowp, part, N);
  scan_partials_kernel<<<1, 1024, 0, stream>>>(part, nb);
  add_off_kernel<<<(N + 256) / 256, 256, 0, stream>>>(rowp, part, N, EP);
  scatter_kernel<<<gEP, 256, 0, stream>>>(ei, rowp, cur, col, E, N);

  convert_wt3_kernel<<<dim3(128, 3), 256, 0, stream>>>(W1, Wt1, W2, Wt2, W3, Wt3);

  int gM = (N + 63) / 64;
  int gN4 = (N + 3) / 4;

  // layer 1 (A = x fp32 converted in-register; alpha fused into epilogue)
  gemm_mfma_kernel<1, 2><<<dim3(gM, 1), 256, 0, stream>>>(
      x, Wt1, as1, ad1, Hb, asrc, adst, N, 128);
  aggregate_concat_kernel<<<gN4, 256, 0, stream>>>(Hb, asrc, adst, b1, rowp, col, Ab, N);
  // layer 2
  gemm_mfma_kernel<0, 2><<<dim3(gM, 1), 256, 0, stream>>>(
      Ab, Wt2, as2, ad2, Hb, asrc, adst, N, 128);
  aggregate_concat_kernel<<<gN4, 256, 0, stream>>>(Hb, asrc, adst, b2, rowp, col, Ab, N);
  // layer 3 (Fout=256, C=64, two col-panels of 2 heads each; mean over heads)
  gemm_mfma_kernel<0, 4><<<dim3(gM, 2), 256, 0, stream>>>(
      Ab, Wt3, as3, ad3, Hb, asrc, adst, N, 256);
  aggregate_mean_kernel<<<N, 128, 0, stream>>>(Hb, asrc, adst, b3, rowp, col, out, N);
}

// Round 11
// 361.915 us; speedup vs baseline: 1.2437x; 1.1224x over previous
//
#include <hip/hip_runtime.h>
#include <hip/hip_fp16.h>

constexpr int HEADS = 4;

typedef _Float16 half8 __attribute__((ext_vector_type(8)));
typedef float f32x4 __attribute__((ext_vector_type(4)));

__device__ __forceinline__ float lrelu(float x) { return x > 0.f ? x : 0.2f * x; }

// ---------------- CSR build (edges grouped by dst; reused by all 3 layers) ----------------

__global__ void count_deg_kernel(const int* __restrict__ ei, int* __restrict__ deg,
                                 int E, int N) {
  int e = blockIdx.x * 256 + threadIdx.x;
  int EP = E + N;
  if (e < EP) {
    int d = (e < E) ? ei[E + e] : (e - E);   // self-loop tail
    atomicAdd(&deg[d], 1);
  }
}

__global__ void scan_block_kernel(const int* __restrict__ deg, int* __restrict__ rowp,
                                  int* __restrict__ partials, int N) {
  __shared__ int sm[1024];
  int t = threadIdx.x;
  int i = blockIdx.x * 1024 + t;
  int v = (i < N) ? deg[i] : 0;
  sm[t] = v;
  __syncthreads();
  for (int off = 1; off < 1024; off <<= 1) {
    int tmp = (t >= off) ? sm[t - off] : 0;
    __syncthreads();
    sm[t] += tmp;
    __syncthreads();
  }
  if (i < N) rowp[i] = sm[t] - v;            // exclusive within block
  if (t == 1023) partials[blockIdx.x] = sm[t];
}

// single 1024-thr block LDS scan (nb <= 1024)
__global__ void scan_partials_kernel(int* partials, int nb) {
  __shared__ int sm[1024];
  int t = threadIdx.x;
  int v = (t < nb) ? partials[t] : 0;
  sm[t] = v;
  __syncthreads();
  for (int off = 1; off < 1024; off <<= 1) {
    int tmp = (t >= off) ? sm[t - off] : 0;
    __syncthreads();
    sm[t] += tmp;
    __syncthreads();
  }
  if (t < nb) partials[t] = sm[t] - v;       // exclusive
}

__global__ void add_off_kernel(int* __restrict__ rowp, const int* __restrict__ partials,
                               int N, int EP) {
  int i = blockIdx.x * 256 + threadIdx.x;
  if (i < N) rowp[i] += partials[i >> 10];
  if (i == 0) rowp[N] = EP;
}

__global__ void scatter_kernel(const int* __restrict__ ei, const int* __restrict__ rowp,
                               int* __restrict__ cursor, int* __restrict__ col,
                               int E, int N) {
  int e = blockIdx.x * 256 + threadIdx.x;
  int EP = E + N;
  if (e < EP) {
    int s, d;
    if (e < E) { s = ei[e]; d = ei[E + e]; }
    else       { s = e - E; d = e - E; }
    int pos = rowp[d] + atomicAdd(&cursor[d], 1);
    col[pos] = s;
  }
}

// ---------------- weight transpose+convert: W [128,Fout] fp32 -> Wt [Fout,128] fp16 ----

__global__ void convert_wt3_kernel(const float* __restrict__ W1, _Float16* __restrict__ Wt1,
                                   const float* __restrict__ W2, _Float16* __restrict__ Wt2,
                                   const float* __restrict__ W3, _Float16* __restrict__ Wt3) {
  const float* W; _Float16* Wt; int Fout;
  if (blockIdx.y == 0)      { W = W1; Wt = Wt1; Fout = 128; }
  else if (blockIdx.y == 1) { W = W2; Wt = Wt2; Fout = 128; }
  else                      { W = W3; Wt = Wt3; Fout = 256; }
  int i = blockIdx.x * 256 + threadIdx.x;
  if (i < 128 * Fout) {
    int c = i >> 7, k = i & 127;
    Wt[c * 128 + k] = (_Float16)W[k * Fout + c];
  }
}

// ---------------- MFMA GEMM v2: B panel staged in LDS (XOR-swizzled) + fused alpha ----

template <int AF32, int CPH>
__global__ __launch_bounds__(256) void gemm_mfma_kernel(
    const void* __restrict__ Xv, const _Float16* __restrict__ Wt,
    const float* __restrict__ a_s, const float* __restrict__ a_d,
    _Float16* __restrict__ O, float* __restrict__ asrc, float* __restrict__ adst,
    int N, int Fout) {
  __shared__ __align__(16) char Bl[32768];      // 128 cols x 128 k x 2B
  const int t = threadIdx.x;
  const int w = t >> 6;
  const int lane = t & 63;
  const int r = lane & 15, g = lane >> 4;
  const int row0 = blockIdx.x * 64 + w * 16;
  const int colpan = blockIdx.y * 128;

#pragma unroll
  for (int i = 0; i < 8; ++i) {
    int lin = i * 256 + t;                      // 16B chunk id
    int c0 = lin >> 4;                          // col 0..127
    int kb = lin & 15;                          // 16B chunk along k
    half8 v = *(const half8*)&Wt[(size_t)(colpan + c0) * 128 + kb * 8];
    int addr = (c0 * 256 + kb * 16) ^ ((c0 & 7) << 4);
    *(half8*)(Bl + addr) = v;
  }
  __syncthreads();

  int rowl = row0 + r;
  if (rowl >= N) rowl = N - 1;                  // clamp for loads; stores guarded

  f32x4 acc[8];
#pragma unroll
  for (int c = 0; c < 8; ++c) acc[c] = {0.f, 0.f, 0.f, 0.f};

#pragma unroll
  for (int s = 0; s < 4; ++s) {
    half8 a;
    if constexpr (AF32) {
      const float* X = (const float*)Xv;
      float4 a0 = *(const float4*)&X[(size_t)rowl * 128 + s * 32 + g * 8];
      float4 a1 = *(const float4*)&X[(size_t)rowl * 128 + s * 32 + g * 8 + 4];
      a = half8{(_Float16)a0.x, (_Float16)a0.y, (_Float16)a0.z, (_Float16)a0.w,
                (_Float16)a1.x, (_Float16)a1.y, (_Float16)a1.z, (_Float16)a1.w};
    } else {
      const _Float16* X = (const _Float16*)Xv;
      a = *(const half8*)&X[(size_t)rowl * 128 + s * 32 + g * 8];
    }
#pragma unroll
    for (int c = 0; c < 8; ++c) {
      int colr = c * 16 + r;
      int addr = (colr * 256 + s * 64 + g * 16) ^ ((colr & 7) << 4);
      half8 b = *(const half8*)(Bl + addr);
      acc[c] = __builtin_amdgcn_mfma_f32_16x16x32_f16(a, b, acc[c], 0, 0, 0);
    }
  }

#pragma unroll
  for (int c = 0; c < 8; ++c) {
    int ocol = colpan + c * 16 + r;
#pragma unroll
    for (int q = 0; q < 4; ++q) {
      int orow = row0 + g * 4 + q;
      if (orow < N) O[(size_t)orow * Fout + ocol] = (_Float16)acc[c][q];
    }
  }

  constexpr int HPP = 8 / CPH;          // heads in this panel
  constexpr int C = CPH * 16;           // channels per head
  const int hbase = blockIdx.y * HPP;
  float ps[4][HPP], pd[4][HPP];
#pragma unroll
  for (int q = 0; q < 4; ++q)
#pragma unroll
    for (int hh = 0; hh < HPP; ++hh) { ps[q][hh] = 0.f; pd[q][hh] = 0.f; }

#pragma unroll
  for (int c = 0; c < 8; ++c) {
    int hh = c / CPH;
    int ch = (c % CPH) * 16 + r;
    float asv = a_s[(hbase + hh) * C + ch];
    float adv = a_d[(hbase + hh) * C + ch];
#pragma unroll
    for (int q = 0; q < 4; ++q) {
      ps[q][hh] += acc[c][q] * asv;
      pd[q][hh] += acc[c][q] * adv;
    }
  }
#pragma unroll
  for (int m = 1; m < 16; m <<= 1) {
#pragma unroll
    for (int q = 0; q < 4; ++q)
#pragma unroll
      for (int hh = 0; hh < HPP; ++hh) {
        ps[q][hh] += __shfl_xor(ps[q][hh], m, 64);
        pd[q][hh] += __shfl_xor(pd[q][hh], m, 64);
      }
  }
  if (r == 0) {
#pragma unroll
    for (int q = 0; q < 4; ++q) {
      int row = row0 + g * 4 + q;
      if (row < N) {
#pragma unroll
        for (int hh = 0; hh < HPP; ++hh) {
          asrc[row * 4 + hbase + hh] = ps[q][hh];
          adst[row * 4 + hbase + hh] = pd[q][hh];
        }
      }
    }
  }
}

// ---------------- aggregation v3: 16B gathers, lane-group edge parallelism ----------------
// concat: 4 waves/block = 4 nodes. Wave = 4 edge-groups x 16 lanes; lane loads half8
// (16B) = channels l16*8..+8 of its group's edge row. head = l16>>2 (exp 4x redundant,
// no cross-lane dep). End: butterfly xor 16,32 combines groups; group 0 writes 16B.

__global__ __launch_bounds__(256) void aggregate_concat_kernel(
    const _Float16* __restrict__ H, const float* __restrict__ asrc,
    const float* __restrict__ adst, const float* __restrict__ bias,
    const int* __restrict__ rowp, const int* __restrict__ col,
    _Float16* __restrict__ out, int N) {
  int n = blockIdx.x * 4 + (threadIdx.x >> 6);
  if (n >= N) return;
  int lane = threadIdx.x & 63;
  int g = lane >> 4;               // edge group 0..3
  int l16 = lane & 15;             // 16B slot in row
  int h = l16 >> 2;                // head
  float ad = adst[n * 4 + h];
  int j = rowp[n], end = rowp[n + 1];
  float acc[8] = {};
  float denom = 0.f;
  for (; j + 8 <= end; j += 8) {   // 8 edges per iter: 2 per group
    int s0 = col[j + g];
    int s1 = col[j + 4 + g];
    float w0 = __expf(lrelu(asrc[s0 * 4 + h] + ad));
    float w1 = __expf(lrelu(asrc[s1 * 4 + h] + ad));
    half8 f0 = *(const half8*)&H[(size_t)s0 * 128 + l16 * 8];
    half8 f1 = *(const half8*)&H[(size_t)s1 * 128 + l16 * 8];
    denom += w0 + w1;
#pragma unroll
    for (int c = 0; c < 8; ++c) acc[c] += w0 * (float)f0[c] + w1 * (float)f1[c];
  }
  for (int base = j; base < end; base += 4) {   // tail: exec-masked, no speculation
    int idx = base + g;
    if (idx < end) {
      int s0 = col[idx];
      float w0 = __expf(lrelu(asrc[s0 * 4 + h] + ad));
      half8 f0 = *(const half8*)&H[(size_t)s0 * 128 + l16 * 8];
      denom += w0;
#pragma unroll
      for (int c = 0; c < 8; ++c) acc[c] += w0 * (float)f0[c];
    }
  }
  // combine the 4 edge-groups
#pragma unroll
  for (int m = 16; m <= 32; m <<= 1) {
    denom += __shfl_xor(denom, m, 64);
#pragma unroll
    for (int c = 0; c < 8; ++c) acc[c] += __shfl_xor(acc[c], m, 64);
  }
  if (g == 0) {
    float inv = 1.f / denom;
    float4 b0 = *(const float4*)&bias[l16 * 8];
    float4 b1 = *(const float4*)&bias[l16 * 8 + 4];
    half8 o;
    o[0] = (_Float16)(acc[0] * inv + b0.x); o[1] = (_Float16)(acc[1] * inv + b0.y);
    o[2] = (_Float16)(acc[2] * inv + b0.z); o[3] = (_Float16)(acc[3] * inv + b0.w);
    o[4] = (_Float16)(acc[4] * inv + b1.x); o[5] = (_Float16)(acc[5] * inv + b1.y);
    o[6] = (_Float16)(acc[6] * inv + b1.z); o[7] = (_Float16)(acc[7] * inv + b1.w);
    *(half8*)&out[(size_t)n * 128 + l16 * 8] = o;
  }
}

// layer 3: rows 512B (256 ch). 2 waves/block = 2 nodes. Wave = 2 edge-groups x 32
// lanes; lane = channels l32*8..+8, head = l32>>3. Butterfly: xor 32 combines groups;
// then per-head normalize, xor 8,16 forms the head-mean; lanes 0..7 write 64 fp32.

__global__ __launch_bounds__(128) void aggregate_mean_kernel(
    const _Float16* __restrict__ H, const float* __restrict__ asrc,
    const float* __restrict__ adst, const float* __restrict__ bias,
    const int* __restrict__ rowp, const int* __restrict__ col,
    float* __restrict__ out, int N) {
  int n = blockIdx.x * 2 + (threadIdx.x >> 6);
  if (n >= N) return;
  int lane = threadIdx.x & 63;
  int g = lane >> 5;               // edge group 0..1
  int l32 = lane & 31;             // 16B slot in row
  int h = l32 >> 3;                // head
  float ad = adst[n * 4 + h];
  int j = rowp[n], end = rowp[n + 1];
  float acc[8] = {};
  float denom = 0.f;
  for (; j + 4 <= end; j += 4) {   // 4 edges per iter: 2 per group
    int s0 = col[j + g];
    int s1 = col[j + 2 + g];
    float w0 = __expf(lrelu(asrc[s0 * 4 + h] + ad));
    float w1 = __expf(lrelu(asrc[s1 * 4 + h] + ad));
    half8 f0 = *(const half8*)&H[(size_t)s0 * 256 + l32 * 8];
    half8 f1 = *(const half8*)&H[(size_t)s1 * 256 + l32 * 8];
    denom += w0 + w1;
#pragma unroll
    for (int c = 0; c < 8; ++c) acc[c] += w0 * (float)f0[c] + w1 * (float)f1[c];
  }
  for (int base = j; base < end; base += 2) {   // tail: exec-masked
    int idx = base + g;
    if (idx < end) {
      int s0 = col[idx];
      float w0 = __expf(lrelu(asrc[s0 * 4 + h] + ad));
      half8 f0 = *(const half8*)&H[(size_t)s0 * 256 + l32 * 8];
      denom += w0;
#pragma unroll
      for (int c = 0; c < 8; ++c) acc[c] += w0 * (float)f0[c];
    }
  }
  // combine the 2 edge-groups
  denom += __shfl_xor(denom, 32, 64);
#pragma unroll
  for (int c = 0; c < 8; ++c) acc[c] += __shfl_xor(acc[c], 32, 64);
  // per-head normalize, then mean across heads (lanes l32 ^ {8,16,24} hold same
  // within-head channels for the other heads)
  float inv = 0.25f / denom;
#pragma unroll
  for (int c = 0; c < 8; ++c) acc[c] *= inv;
#pragma unroll
  for (int m = 8; m <= 16; m <<= 1) {
#pragma unroll
    for (int c = 0; c < 8; ++c) acc[c] += __shfl_xor(acc[c], m, 64);
  }
  if (lane < 8) {
    int cb = lane * 8;
    float4 b0 = *(const float4*)&bias[cb];
    float4 b1 = *(const float4*)&bias[cb + 4];
    float4 o0 = make_float4(acc[0] + b0.x, acc[1] + b0.y, acc[2] + b0.z, acc[3] + b0.w);
    float4 o1 = make_float4(acc[4] + b1.x, acc[5] + b1.y, acc[6] + b1.z, acc[7] + b1.w);
    *(float4*)&out[(size_t)n * 64 + cb] = o0;
    *(float4*)&out[(size_t)n * 64 + cb + 4] = o1;
  }
}

// ---------------- host launch ----------------

extern "C" void kernel_launch(void* const* d_in, const int* in_sizes, int n_in,
                              void* d_out, int out_size, void* d_ws, size_t ws_size,
                              hipStream_t stream) {
  const float* x   = (const float*)d_in[0];
  const int*   ei  = (const int*)d_in[1];
  const float* W1  = (const float*)d_in[2];
  const float* as1 = (const float*)d_in[3];
  const float* ad1 = (const float*)d_in[4];
  const float* b1  = (const float*)d_in[5];
  const float* W2  = (const float*)d_in[6];
  const float* as2 = (const float*)d_in[7];
  const float* ad2 = (const float*)d_in[8];
  const float* b2  = (const float*)d_in[9];
  const float* W3  = (const float*)d_in[10];
  const float* as3 = (const float*)d_in[11];
  const float* ad3 = (const float*)d_in[12];
  const float* b3  = (const float*)d_in[13];
  float* out = (float*)d_out;

  const int N  = in_sizes[0] / 128;
  const int E  = in_sizes[1] / 2;
  const int EP = E + N;

  char* p = (char*)d_ws;
  auto carve = [&](size_t bytes) -> void* {
    void* r = (void*)p;
    p += (bytes + 255) & ~size_t(255);
    return r;
  };
  int*      deg  = (int*)carve(size_t(N) * 4);
  int*      rowp = (int*)carve(size_t(N + 1) * 4);
  int*      cur  = (int*)carve(size_t(N) * 4);
  int*      part = (int*)carve(1024 * 4);
  int*      col  = (int*)carve(size_t(EP) * 4);
  float*    asrc = (float*)carve(size_t(N) * HEADS * 4);
  float*    adst = (float*)carve(size_t(N) * HEADS * 4);
  _Float16* Wt1  = (_Float16*)carve(128 * 128 * 2);
  _Float16* Wt2  = (_Float16*)carve(128 * 128 * 2);
  _Float16* Wt3  = (_Float16*)carve(256 * 128 * 2);
  _Float16* Hb   = (_Float16*)carve(size_t(N) * 256 * 2);  // gemm outputs
  _Float16* Ab   = (_Float16*)carve(size_t(N) * 128 * 2);  // aggregation outputs

  hipMemsetAsync(deg, 0, size_t(N) * 4, stream);
  hipMemsetAsync(cur, 0, size_t(N) * 4, stream);

  int gEP = (EP + 255) / 256;
  count_deg_kernel<<<gEP, 256, 0, stream>>>(ei, deg, E, N);
  int nb = (N + 1023) / 1024;
  scan_block_kernel<<<nb, 1024, 0, stream>>>(deg, rowp, part, N);
  scan_partials_kernel<<<1, 1024, 0, stream>>>(part, nb);
  add_off_kernel<<<(N + 256) / 256, 256, 0, stream>>>(rowp, part, N, EP);
  scatter_kernel<<<gEP, 256, 0, stream>>>(ei, rowp, cur, col, E, N);

  convert_wt3_kernel<<<dim3(128, 3), 256, 0, stream>>>(W1, Wt1, W2, Wt2, W3, Wt3);

  int gM = (N + 63) / 64;
  int gN4 = (N + 3) / 4;
  int gN2 = (N + 1) / 2;

  // layer 1 (A = x fp32 converted in-register; alpha fused into epilogue)
  gemm_mfma_kernel<1, 2><<<dim3(gM, 1), 256, 0, stream>>>(
      x, Wt1, as1, ad1, Hb, asrc, adst, N, 128);
  aggregate_concat_kernel<<<gN4, 256, 0, stream>>>(Hb, asrc, adst, b1, rowp, col, Ab, N);
  // layer 2
  gemm_mfma_kernel<0, 2><<<dim3(gM, 1), 256, 0, stream>>>(
      Ab, Wt2, as2, ad2, Hb, asrc, adst, N, 128);
  aggregate_concat_kernel<<<gN4, 256, 0, stream>>>(Hb, asrc, adst, b2, rowp, col, Ab, N);
  // layer 3 (Fout=256, C=64, two col-panels of 2 heads each; mean over heads)
  gemm_mfma_kernel<0, 4><<<dim3(gM, 2), 256, 0, stream>>>(
      Ab, Wt3, as3, ad3, Hb, asrc, adst, N, 256);
  aggregate_mean_kernel<<<gN2, 128, 0, stream>>>(Hb, asrc, adst, b3, rowp, col, out, N);
}